// Round 8
// baseline (901.204 us; speedup 1.0000x reference)
//
#include <hip/hip_runtime.h>

#define HH 4096
#define BB 4096
#define IND 1024
#define NTOT 16777216   // 4096*4096
#define EPSV 1e-5f

typedef unsigned short u16;
typedef __bf16 bf16x8 __attribute__((ext_vector_type(8)));
typedef float f32x4 __attribute__((ext_vector_type(4)));
typedef u16 u16x8 __attribute__((ext_vector_type(8)));

__device__ __forceinline__ u16 f2bf(float f) {
    unsigned u = __builtin_bit_cast(unsigned, f);
    u += 0x7fffu + ((u >> 16) & 1u);
    return (u16)(u >> 16);
}
__device__ __forceinline__ float bf2f(u16 h) {
    return __builtin_bit_cast(float, ((unsigned)h) << 16);
}

// ---------------- batched f32 -> bf16 conversion (all 8 tensors, 1 launch) ----
#define C0 1048576u
#define C1 5242880u
#define C2 6291456u
#define C3 7340032u
#define C4 8388608u
#define C5 12582912u
#define C6 16777216u
#define C7 20971520u

__global__ __launch_bounds__(256) void cvt_all(
    const float* __restrict__ s0, const float* __restrict__ s1,
    const float* __restrict__ s2, const float* __restrict__ s3,
    const float* __restrict__ s4, const float* __restrict__ s5,
    const float* __restrict__ s6, const float* __restrict__ s7,
    u16* __restrict__ d0, u16* __restrict__ d1, u16* __restrict__ d2,
    u16* __restrict__ d3, u16* __restrict__ d4, u16* __restrict__ d5,
    u16* __restrict__ d6, u16* __restrict__ d7) {
    unsigned g = blockIdx.x * blockDim.x + threadIdx.x;
    const unsigned stride = gridDim.x * blockDim.x;
    for (; g < C7; g += stride) {
        const float* src; u16* dst; unsigned base;
        if (g < C1) {
            if (g < C0) { src = s0; dst = d0; base = 0; }
            else        { src = s1; dst = d1; base = C0; }
        } else if (g < C4) {
            if (g < C2)      { src = s2; dst = d2; base = C1; }
            else if (g < C3) { src = s3; dst = d3; base = C2; }
            else             { src = s4; dst = d4; base = C3; }
        } else {
            if (g < C5)      { src = s5; dst = d5; base = C4; }
            else if (g < C6) { src = s6; dst = d6; base = C5; }
            else             { src = s7; dst = d7; base = C6; }
        }
        const unsigned i4 = (g - base) * 4;
        f32x4 v = *(const f32x4*)(src + i4);
        unsigned p0 = (unsigned)f2bf(v[0]) | ((unsigned)f2bf(v[1]) << 16);
        unsigned p1 = (unsigned)f2bf(v[2]) | ((unsigned)f2bf(v[3]) << 16);
        *(uint2*)(dst + i4) = make_uint2(p0, p1);
    }
}

// ---------------- fused GRU GEMM (R4 memory structure, 512-thread blocks) ----
// 128x128 tile, BK=64, st_16x32 swizzled LDS (0 conflicts, proven R3-R5),
// 16x16x32 MFMA (proven layout), r-gate via global scratch (proven R4).
// R8: 8 waves/block, each wave owns 64x32 of C -> acc 32 AGPR, unified ~80 regs
// -> 3 blocks/CU x 8 waves = 24 waves/CU (was 16). Same staging + swizzle.

__device__ __forceinline__ void stage_tile(const u16* __restrict__ g, int ld, int row0, int k0,
                                           u16* lds, int tid) {
    const int l = tid & 63, w = tid >> 6;
#pragma unroll
    for (int j = 0; j < 2; ++j) {
        const int sub = j * 8 + w;                  // 0..15, wave-uniform
        const int d = l << 4;                       // linear byte chunk in subtile
        const int lin = d ^ (((d >> 9) & 1) << 5);  // involution: source element
        const int r = ((sub >> 1) << 4) | (lin >> 6);
        const int c = ((sub & 1) << 5) | ((lin & 63) >> 1);
        const u16* ga = g + (size_t)(row0 + r) * ld + (k0 + c);
        __builtin_amdgcn_global_load_lds(
            (const __attribute__((address_space(1))) unsigned*)ga,
            (__attribute__((address_space(3))) unsigned*)(lds + (sub << 9)),
            16, 0, 0);
    }
}

__device__ __forceinline__ void zero_acc(f32x4 (&acc)[4][2]) {
#pragma unroll
    for (int i = 0; i < 4; ++i)
#pragma unroll
        for (int j = 0; j < 2; ++j) {
            f32x4 zz = {0.f, 0.f, 0.f, 0.f};
            acc[i][j] = zz;
        }
}

__device__ __forceinline__ void run_phase(const u16* __restrict__ A, int row0a,
                                          const u16* __restrict__ B, int ld, int Klen,
                                          u16* Alds, u16* Blds,
                                          f32x4 (&acc)[4][2], int tid) {
    const int l = tid & 63;
    const int wid = tid >> 6;
    const int wr = wid >> 2, wc = wid & 3;   // wave: 64-row half x 32-col strip
    const int lr = l & 15, lq = l >> 4;
    // lane-invariant swizzled offset within a subtile (u16 units)
    const int swzh = (((lr << 6) | (lq << 4)) ^ ((lr & 8) << 2)) >> 1;
    for (int k0 = 0; k0 < Klen; k0 += 64) {
        stage_tile(A, ld, row0a, k0, Alds, tid);
        stage_tile(B, ld, 0, k0, Blds, tid);
        __syncthreads();
#pragma unroll
        for (int kk = 0; kk < 2; ++kk) {
            bf16x8 af[4], bfr[2];
#pragma unroll
            for (int i = 0; i < 4; ++i)
                af[i] = *(const bf16x8*)(Alds + ((wr * 8 + i * 2 + kk) << 9) + swzh);
#pragma unroll
            for (int j = 0; j < 2; ++j)
                bfr[j] = *(const bf16x8*)(Blds + ((wc * 4 + j * 2 + kk) << 9) + swzh);
#pragma unroll
            for (int i = 0; i < 4; ++i)
#pragma unroll
                for (int j = 0; j < 2; ++j)
                    acc[i][j] = __builtin_amdgcn_mfma_f32_16x16x32_bf16(af[i], bfr[j], acc[i][j], 0, 0, 0);
        }
        __syncthreads();
    }
}

__global__ __launch_bounds__(512, 6) void gru_gemm(
    const u16* __restrict__ xbf, const u16* __restrict__ hbf,
    const u16* __restrict__ Wr, const u16* __restrict__ Ur,
    const u16* __restrict__ Wz, const u16* __restrict__ Uz,
    const u16* __restrict__ Wh, const u16* __restrict__ Uh,
    const float* __restrict__ Wr_b, const float* __restrict__ Ur_b,
    const float* __restrict__ Wz_b, const float* __restrict__ Uz_b,
    const float* __restrict__ Wh_b, const float* __restrict__ Uh_b,
    u16* __restrict__ r_out, u16* __restrict__ z_out,
    u16* __restrict__ hpre_out, float* __restrict__ partials) {
    __shared__ __align__(16) u16 Alds[128 * 64];
    __shared__ __align__(16) u16 Blds[128 * 64];
    __shared__ float redS[8], redSS[8];

    const int tid = threadIdx.x;
    const int m0 = blockIdx.x * 128, n0 = blockIdx.y * 128;
    const int l = tid & 63, wid = tid >> 6;
    const int wr = wid >> 2, wc = wid & 3;
    const int lr = l & 15, lq = l >> 4;

    f32x4 acc[4][2];

    // ---- reset gate: r = sigmoid(Wr x + Ur h + br + bur) -> GLOBAL scratch ----
    zero_acc(acc);
    run_phase(xbf, m0, Wr + (size_t)n0 * IND, IND, IND, Alds, Blds, acc, tid);
    run_phase(hbf, m0, Ur + (size_t)n0 * HH, HH, HH, Alds, Blds, acc, tid);
#pragma unroll
    for (int j = 0; j < 2; ++j) {
        int col = n0 + wc * 32 + j * 16 + lr;
        float bias = Wr_b[col] + Ur_b[col];
#pragma unroll
        for (int i = 0; i < 4; ++i) {
            int rowb = m0 + wr * 64 + i * 16 + lq * 4;
#pragma unroll
            for (int q = 0; q < 4; ++q) {
                float rv = 1.f / (1.f + __expf(-(acc[i][j][q] + bias)));
                r_out[(size_t)(rowb + q) * HH + col] = f2bf(rv);
            }
        }
    }

    // ---- update gate: z = sigmoid(Wz x + Uz h + bz + buz) ----
    zero_acc(acc);
    run_phase(xbf, m0, Wz + (size_t)n0 * IND, IND, IND, Alds, Blds, acc, tid);
    run_phase(hbf, m0, Uz + (size_t)n0 * HH, HH, HH, Alds, Blds, acc, tid);
#pragma unroll
    for (int j = 0; j < 2; ++j) {
        int col = n0 + wc * 32 + j * 16 + lr;
        float bias = Wz_b[col] + Uz_b[col];
#pragma unroll
        for (int i = 0; i < 4; ++i) {
            int rowb = m0 + wr * 64 + i * 16 + lq * 4;
#pragma unroll
            for (int q = 0; q < 4; ++q) {
                float zv = 1.f / (1.f + __expf(-(acc[i][j][q] + bias)));
                z_out[(size_t)(rowb + q) * HH + col] = f2bf(zv);
            }
        }
    }

    // ---- h_pre = (Wh x + bwh) + r*(Uh h + buh) ----
    zero_acc(acc);
    run_phase(hbf, m0, Uh + (size_t)n0 * HH, HH, HH, Alds, Blds, acc, tid);
#pragma unroll
    for (int j = 0; j < 2; ++j) {
        int col = n0 + wc * 32 + j * 16 + lr;
        float bias = Uh_b[col];
#pragma unroll
        for (int i = 0; i < 4; ++i) {
            int rowb = m0 + wr * 64 + i * 16 + lq * 4;
#pragma unroll
            for (int q = 0; q < 4; ++q) {
                float rv = bf2f(r_out[(size_t)(rowb + q) * HH + col]);
                acc[i][j][q] = rv * (acc[i][j][q] + bias);
            }
        }
    }
    // accumulate Wh x on top (MFMA C-in is linear)
    run_phase(xbf, m0, Wh + (size_t)n0 * IND, IND, IND, Alds, Blds, acc, tid);

    float s = 0.f, ss = 0.f;
#pragma unroll
    for (int j = 0; j < 2; ++j) {
        int col = n0 + wc * 32 + j * 16 + lr;
        float bias = Wh_b[col];
#pragma unroll
        for (int i = 0; i < 4; ++i) {
            int rowb = m0 + wr * 64 + i * 16 + lq * 4;
#pragma unroll
            for (int q = 0; q < 4; ++q) {
                float hv = acc[i][j][q] + bias;
                hpre_out[(size_t)(rowb + q) * HH + col] = f2bf(hv);
                s += hv;
                ss += hv * hv;
            }
        }
    }
    // deterministic block partials for global mean/var
#pragma unroll
    for (int off = 32; off; off >>= 1) {
        s += __shfl_down(s, off, 64);
        ss += __shfl_down(ss, off, 64);
    }
    if (l == 0) { redS[wid] = s; redSS[wid] = ss; }
    __syncthreads();
    if (tid == 0) {
        int bid = blockIdx.y * 32 + blockIdx.x;
        float S = 0.f, SS = 0.f;
#pragma unroll
        for (int i = 0; i < 8; ++i) { S += redS[i]; SS += redSS[i]; }
        partials[2 * bid] = S;
        partials[2 * bid + 1] = SS;
    }
}

// ---------------- stats reduce ----------------
__global__ void reduce_stats(const float* __restrict__ partials, int nblk,
                             const float* __restrict__ gamma, const float* __restrict__ beta,
                             float* __restrict__ stats) {
    __shared__ float rs[4], rss[4];
    int tid = threadIdx.x;
    float s = 0.f, ss = 0.f;
    for (int i = tid; i < nblk; i += blockDim.x) {
        s += partials[2 * i];
        ss += partials[2 * i + 1];
    }
#pragma unroll
    for (int off = 32; off; off >>= 1) {
        s += __shfl_down(s, off, 64);
        ss += __shfl_down(ss, off, 64);
    }
    if ((tid & 63) == 0) { rs[tid >> 6] = s; rss[tid >> 6] = ss; }
    __syncthreads();
    if (tid == 0) {
        float S = rs[0] + rs[1] + rs[2] + rs[3];
        float SS = rss[0] + rss[1] + rss[2] + rss[3];
        float mean = S / (float)NTOT;
        float var = SS / (float)NTOT - mean * mean;
        float scale = gamma[0] * rsqrtf(var + EPSV);
        stats[0] = scale;
        stats[1] = beta[0] - mean * scale;
    }
}

// ---------------- finalize: BN + blend + 4-way GEMV head (bf16 hidden) ------
__global__ __launch_bounds__(256) void finalize(
    const u16* __restrict__ z, const u16* __restrict__ hpre,
    const u16* __restrict__ hidden, const float* __restrict__ out_w,
    const float* __restrict__ out_b, const float* __restrict__ stats,
    float* __restrict__ d_out) {
    __shared__ float red[4][4];
    const int b = blockIdx.x, t = threadIdx.x;
    const float scale = stats[0], shift = stats[1];
    const size_t row = (size_t)b * HH;
    float so[4] = {0.f, 0.f, 0.f, 0.f};
#pragma unroll
    for (int jj = 0; jj < 2; ++jj) {
        int h0 = jj * 2048 + t * 8;
        u16x8 zv = *(const u16x8*)(z + row + h0);
        u16x8 hp = *(const u16x8*)(hpre + row + h0);
        u16x8 hd = *(const u16x8*)(hidden + row + h0);
        f32x4 o0, o1;
#pragma unroll
        for (int e = 0; e < 8; ++e) {
            float zf = bf2f(zv[e]);
            float pv = bf2f(hp[e]) * scale + shift;
            pv = pv > 0.f ? pv : 0.f;
            float hf = bf2f(hd[e]);
            float cs = (1.f - zf) * hf + zf * pv;
            if (e < 4) o0[e] = cs; else o1[e - 4] = cs;
#pragma unroll
            for (int o = 0; o < 4; ++o)
                so[o] += cs * __ldg(out_w + o * HH + h0 + e);
        }
        *(f32x4*)(d_out + row + h0) = o0;
        *(f32x4*)(d_out + row + h0 + 4) = o1;
    }
#pragma unroll
    for (int off = 32; off; off >>= 1)
#pragma unroll
        for (int o = 0; o < 4; ++o) so[o] += __shfl_down(so[o], off, 64);
    if ((t & 63) == 0)
#pragma unroll
        for (int o = 0; o < 4; ++o) red[t >> 6][o] = so[o];
    __syncthreads();
    if (t < 4) {
        float v = red[0][t] + red[1][t] + red[2][t] + red[3][t] + __ldg(out_b + t);
        d_out[(size_t)NTOT + (size_t)t * BB + b] = v;
    }
}

extern "C" void kernel_launch(void* const* d_in, const int* in_sizes, int n_in,
                              void* d_out, int out_size, void* d_ws, size_t ws_size,
                              hipStream_t stream) {
    const float* input = (const float*)d_in[0];
    const float* hidden = (const float*)d_in[3];
    const float* Wr_w = (const float*)d_in[4];  const float* Wr_b = (const float*)d_in[5];
    const float* Ur_w = (const float*)d_in[6];  const float* Ur_b = (const float*)d_in[7];
    const float* Wz_w = (const float*)d_in[8];  const float* Wz_b = (const float*)d_in[9];
    const float* Uz_w = (const float*)d_in[10]; const float* Uz_b = (const float*)d_in[11];
    const float* Wh_w = (const float*)d_in[12]; const float* Wh_b = (const float*)d_in[13];
    const float* Uh_w = (const float*)d_in[14]; const float* Uh_b = (const float*)d_in[15];
    const float* out_w = (const float*)d_in[16]; const float* out_b = (const float*)d_in[17];
    const float* gamma = (const float*)d_in[18]; const float* beta = (const float*)d_in[19];

    char* ws = (char*)d_ws;
    size_t off = 0;
    auto alloc = [&](size_t bytes) {
        void* p = ws + off;
        off = (off + bytes + 255) & ~(size_t)255;
        return p;
    };
    u16* xbf = (u16*)alloc((size_t)BB * IND * 2);
    u16* hbf = (u16*)alloc((size_t)BB * HH * 2);
    u16* wr = (u16*)alloc((size_t)HH * IND * 2);
    u16* wz = (u16*)alloc((size_t)HH * IND * 2);
    u16* wh = (u16*)alloc((size_t)HH * IND * 2);
    u16* ur = (u16*)alloc((size_t)HH * HH * 2);
    u16* uz = (u16*)alloc((size_t)HH * HH * 2);
    u16* uh = (u16*)alloc((size_t)HH * HH * 2);
    u16* zpl = (u16*)alloc((size_t)BB * HH * 2);
    u16* hpl = (u16*)alloc((size_t)BB * HH * 2);
    float* partials = (float*)alloc(2048 * sizeof(float));
    float* stats = (float*)alloc(16);

    // r-plane scratch in d_out's first 32MB (consumed before finalize
    // overwrites all of d_out) -- proven safe in R2/R4.
    u16* rpl = (u16*)d_out;

    cvt_all<<<4096, 256, 0, stream>>>(input, hidden, Wr_w, Wz_w, Wh_w, Ur_w, Uz_w, Uh_w,
                                      xbf, hbf, wr, wz, wh, ur, uz, uh);

    gru_gemm<<<dim3(32, 32), 512, 0, stream>>>(xbf, hbf, wr, ur, wz, uz, wh, uh,
                                               Wr_b, Ur_b, Wz_b, Uz_b, Wh_b, Uh_b,
                                               rpl, zpl, hpl, partials);
    reduce_stats<<<1, 256, 0, stream>>>(partials, 1024, gamma, beta, stats);
    finalize<<<BB, 256, 0, stream>>>(zpl, hpl, hbf, out_w, out_b, stats, (float*)d_out);
}

// Round 9
// 722.113 us; speedup vs baseline: 1.2480x; 1.2480x over previous
//
#include <hip/hip_runtime.h>

#define HH 4096
#define BB 4096
#define IND 1024
#define NTOT 16777216   // 4096*4096
#define EPSV 1e-5f

typedef unsigned short u16;
typedef __bf16 bf16x8 __attribute__((ext_vector_type(8)));
typedef float f32x4 __attribute__((ext_vector_type(4)));
typedef u16 u16x8 __attribute__((ext_vector_type(8)));

__device__ __forceinline__ u16 f2bf(float f) {
    unsigned u = __builtin_bit_cast(unsigned, f);
    u += 0x7fffu + ((u >> 16) & 1u);
    return (u16)(u >> 16);
}
__device__ __forceinline__ float bf2f(u16 h) {
    return __builtin_bit_cast(float, ((unsigned)h) << 16);
}

// ---------------- batched f32 -> bf16 conversion (all 8 tensors, 1 launch) ----
#define C0 1048576u
#define C1 5242880u
#define C2 6291456u
#define C3 7340032u
#define C4 8388608u
#define C5 12582912u
#define C6 16777216u
#define C7 20971520u

__global__ __launch_bounds__(256) void cvt_all(
    const float* __restrict__ s0, const float* __restrict__ s1,
    const float* __restrict__ s2, const float* __restrict__ s3,
    const float* __restrict__ s4, const float* __restrict__ s5,
    const float* __restrict__ s6, const float* __restrict__ s7,
    u16* __restrict__ d0, u16* __restrict__ d1, u16* __restrict__ d2,
    u16* __restrict__ d3, u16* __restrict__ d4, u16* __restrict__ d5,
    u16* __restrict__ d6, u16* __restrict__ d7) {
    unsigned g = blockIdx.x * blockDim.x + threadIdx.x;
    const unsigned stride = gridDim.x * blockDim.x;
    for (; g < C7; g += stride) {
        const float* src; u16* dst; unsigned base;
        if (g < C1) {
            if (g < C0) { src = s0; dst = d0; base = 0; }
            else        { src = s1; dst = d1; base = C0; }
        } else if (g < C4) {
            if (g < C2)      { src = s2; dst = d2; base = C1; }
            else if (g < C3) { src = s3; dst = d3; base = C2; }
            else             { src = s4; dst = d4; base = C3; }
        } else {
            if (g < C5)      { src = s5; dst = d5; base = C4; }
            else if (g < C6) { src = s6; dst = d6; base = C5; }
            else             { src = s7; dst = d7; base = C6; }
        }
        const unsigned i4 = (g - base) * 4;
        f32x4 v = *(const f32x4*)(src + i4);
        unsigned p0 = (unsigned)f2bf(v[0]) | ((unsigned)f2bf(v[1]) << 16);
        unsigned p1 = (unsigned)f2bf(v[2]) | ((unsigned)f2bf(v[3]) << 16);
        *(uint2*)(dst + i4) = make_uint2(p0, p1);
    }
}

// ---------------- fused GRU GEMM (R4 configuration — proven best) ----------
// 128x128 tile, BK=64, 4 waves (64x64 C each), st_16x32 swizzled LDS
// (0 bank conflicts), 16x16x32 MFMA, r-gate via global scratch,
// __launch_bounds__(256,4): VGPR 64 + AGPR 64 = 128 unified -> 4 blocks/CU.

__device__ __forceinline__ void stage_tile(const u16* __restrict__ g, int ld, int row0, int k0,
                                           u16* lds, int tid) {
    const int l = tid & 63, w = tid >> 6;
#pragma unroll
    for (int j = 0; j < 4; ++j) {
        const int sub = j * 4 + w;                  // 0..15, wave-uniform
        const int d = l << 4;                       // linear byte chunk in subtile
        const int lin = d ^ (((d >> 9) & 1) << 5);  // involution: source element
        const int r = ((sub >> 1) << 4) | (lin >> 6);
        const int c = ((sub & 1) << 5) | ((lin & 63) >> 1);
        const u16* ga = g + (size_t)(row0 + r) * ld + (k0 + c);
        __builtin_amdgcn_global_load_lds(
            (const __attribute__((address_space(1))) unsigned*)ga,
            (__attribute__((address_space(3))) unsigned*)(lds + (sub << 9)),
            16, 0, 0);
    }
}

__device__ __forceinline__ void zero_acc(f32x4 (&acc)[4][4]) {
#pragma unroll
    for (int i = 0; i < 4; ++i)
#pragma unroll
        for (int j = 0; j < 4; ++j) {
            f32x4 zz = {0.f, 0.f, 0.f, 0.f};
            acc[i][j] = zz;
        }
}

__device__ __forceinline__ void run_phase(const u16* __restrict__ A, int row0a,
                                          const u16* __restrict__ B, int ld, int Klen,
                                          u16* Alds, u16* Blds,
                                          f32x4 (&acc)[4][4], int tid) {
    const int l = tid & 63;
    const int wid = tid >> 6;
    const int wr = wid >> 1, wc = wid & 1;
    const int lr = l & 15, lq = l >> 4;
    // lane-invariant swizzled offset within a subtile (u16 units)
    const int swzh = (((lr << 6) | (lq << 4)) ^ ((lr & 8) << 2)) >> 1;
    for (int k0 = 0; k0 < Klen; k0 += 64) {
        stage_tile(A, ld, row0a, k0, Alds, tid);
        stage_tile(B, ld, 0, k0, Blds, tid);
        __syncthreads();
#pragma unroll
        for (int kk = 0; kk < 2; ++kk) {
            bf16x8 af[4], bfr[4];
#pragma unroll
            for (int i = 0; i < 4; ++i)
                af[i] = *(const bf16x8*)(Alds + ((wr * 8 + i * 2 + kk) << 9) + swzh);
#pragma unroll
            for (int j = 0; j < 4; ++j)
                bfr[j] = *(const bf16x8*)(Blds + ((wc * 8 + j * 2 + kk) << 9) + swzh);
#pragma unroll
            for (int i = 0; i < 4; ++i)
#pragma unroll
                for (int j = 0; j < 4; ++j)
                    acc[i][j] = __builtin_amdgcn_mfma_f32_16x16x32_bf16(af[i], bfr[j], acc[i][j], 0, 0, 0);
        }
        __syncthreads();
    }
}

__global__ __launch_bounds__(256, 4) void gru_gemm(
    const u16* __restrict__ xbf, const u16* __restrict__ hbf,
    const u16* __restrict__ Wr, const u16* __restrict__ Ur,
    const u16* __restrict__ Wz, const u16* __restrict__ Uz,
    const u16* __restrict__ Wh, const u16* __restrict__ Uh,
    const float* __restrict__ Wr_b, const float* __restrict__ Ur_b,
    const float* __restrict__ Wz_b, const float* __restrict__ Uz_b,
    const float* __restrict__ Wh_b, const float* __restrict__ Uh_b,
    u16* __restrict__ r_out, u16* __restrict__ z_out,
    u16* __restrict__ hpre_out, float* __restrict__ partials) {
    __shared__ __align__(16) u16 Alds[128 * 64];
    __shared__ __align__(16) u16 Blds[128 * 64];
    __shared__ float redS[4], redSS[4];

    const int tid = threadIdx.x;
    const int m0 = blockIdx.x * 128, n0 = blockIdx.y * 128;
    const int l = tid & 63, wid = tid >> 6;
    const int wr = wid >> 1, wc = wid & 1;
    const int lr = l & 15, lq = l >> 4;

    f32x4 acc[4][4];

    // ---- reset gate: r = sigmoid(Wr x + Ur h + br + bur) -> GLOBAL scratch ----
    zero_acc(acc);
    run_phase(xbf, m0, Wr + (size_t)n0 * IND, IND, IND, Alds, Blds, acc, tid);
    run_phase(hbf, m0, Ur + (size_t)n0 * HH, HH, HH, Alds, Blds, acc, tid);
#pragma unroll
    for (int j = 0; j < 4; ++j) {
        int col = n0 + wc * 64 + j * 16 + lr;
        float bias = Wr_b[col] + Ur_b[col];
#pragma unroll
        for (int i = 0; i < 4; ++i) {
            int rowb = m0 + wr * 64 + i * 16 + lq * 4;
#pragma unroll
            for (int q = 0; q < 4; ++q) {
                float rv = 1.f / (1.f + __expf(-(acc[i][j][q] + bias)));
                r_out[(size_t)(rowb + q) * HH + col] = f2bf(rv);
            }
        }
    }

    // ---- update gate: z = sigmoid(Wz x + Uz h + bz + buz) ----
    zero_acc(acc);
    run_phase(xbf, m0, Wz + (size_t)n0 * IND, IND, IND, Alds, Blds, acc, tid);
    run_phase(hbf, m0, Uz + (size_t)n0 * HH, HH, HH, Alds, Blds, acc, tid);
#pragma unroll
    for (int j = 0; j < 4; ++j) {
        int col = n0 + wc * 64 + j * 16 + lr;
        float bias = Wz_b[col] + Uz_b[col];
#pragma unroll
        for (int i = 0; i < 4; ++i) {
            int rowb = m0 + wr * 64 + i * 16 + lq * 4;
#pragma unroll
            for (int q = 0; q < 4; ++q) {
                float zv = 1.f / (1.f + __expf(-(acc[i][j][q] + bias)));
                z_out[(size_t)(rowb + q) * HH + col] = f2bf(zv);
            }
        }
    }

    // ---- h_pre = (Wh x + bwh) + r*(Uh h + buh) ----
    zero_acc(acc);
    run_phase(hbf, m0, Uh + (size_t)n0 * HH, HH, HH, Alds, Blds, acc, tid);
#pragma unroll
    for (int j = 0; j < 4; ++j) {
        int col = n0 + wc * 64 + j * 16 + lr;
        float bias = Uh_b[col];
#pragma unroll
        for (int i = 0; i < 4; ++i) {
            int rowb = m0 + wr * 64 + i * 16 + lq * 4;
#pragma unroll
            for (int q = 0; q < 4; ++q) {
                float rv = bf2f(r_out[(size_t)(rowb + q) * HH + col]);
                acc[i][j][q] = rv * (acc[i][j][q] + bias);
            }
        }
    }
    // accumulate Wh x on top (MFMA C-in is linear)
    run_phase(xbf, m0, Wh + (size_t)n0 * IND, IND, IND, Alds, Blds, acc, tid);

    float s = 0.f, ss = 0.f;
#pragma unroll
    for (int j = 0; j < 4; ++j) {
        int col = n0 + wc * 64 + j * 16 + lr;
        float bias = Wh_b[col];
#pragma unroll
        for (int i = 0; i < 4; ++i) {
            int rowb = m0 + wr * 64 + i * 16 + lq * 4;
#pragma unroll
            for (int q = 0; q < 4; ++q) {
                float hv = acc[i][j][q] + bias;
                hpre_out[(size_t)(rowb + q) * HH + col] = f2bf(hv);
                s += hv;
                ss += hv * hv;
            }
        }
    }
    // deterministic block partials for global mean/var
#pragma unroll
    for (int off = 32; off; off >>= 1) {
        s += __shfl_down(s, off, 64);
        ss += __shfl_down(ss, off, 64);
    }
    if (l == 0) { redS[wid] = s; redSS[wid] = ss; }
    __syncthreads();
    if (tid == 0) {
        int bid = blockIdx.y * 32 + blockIdx.x;
        partials[2 * bid] = redS[0] + redS[1] + redS[2] + redS[3];
        partials[2 * bid + 1] = redSS[0] + redSS[1] + redSS[2] + redSS[3];
    }
}

// ---------------- stats reduce ----------------
__global__ void reduce_stats(const float* __restrict__ partials, int nblk,
                             const float* __restrict__ gamma, const float* __restrict__ beta,
                             float* __restrict__ stats) {
    __shared__ float rs[4], rss[4];
    int tid = threadIdx.x;
    float s = 0.f, ss = 0.f;
    for (int i = tid; i < nblk; i += blockDim.x) {
        s += partials[2 * i];
        ss += partials[2 * i + 1];
    }
#pragma unroll
    for (int off = 32; off; off >>= 1) {
        s += __shfl_down(s, off, 64);
        ss += __shfl_down(ss, off, 64);
    }
    if ((tid & 63) == 0) { rs[tid >> 6] = s; rss[tid >> 6] = ss; }
    __syncthreads();
    if (tid == 0) {
        float S = rs[0] + rs[1] + rs[2] + rs[3];
        float SS = rss[0] + rss[1] + rss[2] + rss[3];
        float mean = S / (float)NTOT;
        float var = SS / (float)NTOT - mean * mean;
        float scale = gamma[0] * rsqrtf(var + EPSV);
        stats[0] = scale;
        stats[1] = beta[0] - mean * scale;
    }
}

// ---------------- finalize: BN + blend + 4-way GEMV head (bf16 hidden) ------
__global__ __launch_bounds__(256) void finalize(
    const u16* __restrict__ z, const u16* __restrict__ hpre,
    const u16* __restrict__ hidden, const float* __restrict__ out_w,
    const float* __restrict__ out_b, const float* __restrict__ stats,
    float* __restrict__ d_out) {
    __shared__ float red[4][4];
    const int b = blockIdx.x, t = threadIdx.x;
    const float scale = stats[0], shift = stats[1];
    const size_t row = (size_t)b * HH;
    float so[4] = {0.f, 0.f, 0.f, 0.f};
#pragma unroll
    for (int jj = 0; jj < 2; ++jj) {
        int h0 = jj * 2048 + t * 8;
        u16x8 zv = *(const u16x8*)(z + row + h0);
        u16x8 hp = *(const u16x8*)(hpre + row + h0);
        u16x8 hd = *(const u16x8*)(hidden + row + h0);
        f32x4 o0, o1;
#pragma unroll
        for (int e = 0; e < 8; ++e) {
            float zf = bf2f(zv[e]);
            float pv = bf2f(hp[e]) * scale + shift;
            pv = pv > 0.f ? pv : 0.f;
            float hf = bf2f(hd[e]);
            float cs = (1.f - zf) * hf + zf * pv;
            if (e < 4) o0[e] = cs; else o1[e - 4] = cs;
#pragma unroll
            for (int o = 0; o < 4; ++o)
                so[o] += cs * __ldg(out_w + o * HH + h0 + e);
        }
        *(f32x4*)(d_out + row + h0) = o0;
        *(f32x4*)(d_out + row + h0 + 4) = o1;
    }
#pragma unroll
    for (int off = 32; off; off >>= 1)
#pragma unroll
        for (int o = 0; o < 4; ++o) so[o] += __shfl_down(so[o], off, 64);
    if ((t & 63) == 0)
#pragma unroll
        for (int o = 0; o < 4; ++o) red[t >> 6][o] = so[o];
    __syncthreads();
    if (t < 4) {
        float v = red[0][t] + red[1][t] + red[2][t] + red[3][t] + __ldg(out_b + t);
        d_out[(size_t)NTOT + (size_t)t * BB + b] = v;
    }
}

extern "C" void kernel_launch(void* const* d_in, const int* in_sizes, int n_in,
                              void* d_out, int out_size, void* d_ws, size_t ws_size,
                              hipStream_t stream) {
    const float* input = (const float*)d_in[0];
    const float* hidden = (const float*)d_in[3];
    const float* Wr_w = (const float*)d_in[4];  const float* Wr_b = (const float*)d_in[5];
    const float* Ur_w = (const float*)d_in[6];  const float* Ur_b = (const float*)d_in[7];
    const float* Wz_w = (const float*)d_in[8];  const float* Wz_b = (const float*)d_in[9];
    const float* Uz_w = (const float*)d_in[10]; const float* Uz_b = (const float*)d_in[11];
    const float* Wh_w = (const float*)d_in[12]; const float* Wh_b = (const float*)d_in[13];
    const float* Uh_w = (const float*)d_in[14]; const float* Uh_b = (const float*)d_in[15];
    const float* out_w = (const float*)d_in[16]; const float* out_b = (const float*)d_in[17];
    const float* gamma = (const float*)d_in[18]; const float* beta = (const float*)d_in[19];

    char* ws = (char*)d_ws;
    size_t off = 0;
    auto alloc = [&](size_t bytes) {
        void* p = ws + off;
        off = (off + bytes + 255) & ~(size_t)255;
        return p;
    };
    u16* xbf = (u16*)alloc((size_t)BB * IND * 2);
    u16* hbf = (u16*)alloc((size_t)BB * HH * 2);
    u16* wr = (u16*)alloc((size_t)HH * IND * 2);
    u16* wz = (u16*)alloc((size_t)HH * IND * 2);
    u16* wh = (u16*)alloc((size_t)HH * IND * 2);
    u16* ur = (u16*)alloc((size_t)HH * HH * 2);
    u16* uz = (u16*)alloc((size_t)HH * HH * 2);
    u16* uh = (u16*)alloc((size_t)HH * HH * 2);
    u16* zpl = (u16*)alloc((size_t)BB * HH * 2);
    u16* hpl = (u16*)alloc((size_t)BB * HH * 2);
    float* partials = (float*)alloc(2048 * sizeof(float));
    float* stats = (float*)alloc(16);

    // r-plane scratch in d_out's first 32MB (consumed before finalize
    // overwrites all of d_out) -- proven safe in R2/R4.
    u16* rpl = (u16*)d_out;

    cvt_all<<<4096, 256, 0, stream>>>(input, hidden, Wr_w, Wz_w, Wh_w, Ur_w, Uz_w, Uh_w,
                                      xbf, hbf, wr, wz, wh, ur, uz, uh);

    gru_gemm<<<dim3(32, 32), 256, 0, stream>>>(xbf, hbf, wr, ur, wz, uz, wh, uh,
                                               Wr_b, Ur_b, Wz_b, Uz_b, Wh_b, Uh_b,
                                               rpl, zpl, hpl, partials);
    reduce_stats<<<1, 256, 0, stream>>>(partials, 1024, gamma, beta, stats);
    finalize<<<BB, 256, 0, stream>>>(zpl, hpl, hbf, out_w, out_b, stats, (float*)d_out);
}